// Round 1
// baseline (434.165 us; speedup 1.0000x reference)
//
#include <hip/hip_runtime.h>
#include <math.h>

#define D_IN   128
#define D_OUT  32
#define NEG_SLOPE 0.2f
#define DROP_P 0.6f
#define KEEP_SCALE 2.5f   // 1/(1-0.6)

__device__ __forceinline__ void atomicMaxF(float* addr, float v) {
    // standard float-max via int/uint atomics (works for mixed signs)
    if (v >= 0.0f) atomicMax((int*)addr, __float_as_int(v));
    else           atomicMin((unsigned int*)addr, __float_as_uint(v));
}

// K0: fold attention vectors: v_src[k] = sum_c W_src[k,c]*att_src[c]; same for dst
__global__ void k_fold(const float* __restrict__ W_src, const float* __restrict__ W_dst,
                       const float* __restrict__ att_src, const float* __restrict__ att_dst,
                       float* __restrict__ v_src, float* __restrict__ v_dst) {
    int k = threadIdx.x;              // 0..127
    if (k >= D_IN) return;
    float s = 0.f, d = 0.f;
    #pragma unroll
    for (int c = 0; c < D_OUT; ++c) {
        s += W_src[k * D_OUT + c] * att_src[c];
        d += W_dst[k * D_OUT + c] * att_dst[c];
    }
    v_src[k] = s;
    v_dst[k] = d;
}

// KA: per-node — dropout, h_src = xd@W_src, a_src/a_dst via folded vectors,
//     init e_max/denom/agg. 8 nodes per 256-thread block, 32 lanes per node.
__global__ __launch_bounds__(256) void k_nodes(
    const float* __restrict__ x, const float* __restrict__ drop_u,
    const float* __restrict__ W_src,
    const float* __restrict__ v_src, const float* __restrict__ v_dst,
    float* __restrict__ h_src, float* __restrict__ a_src, float* __restrict__ a_dst,
    float* __restrict__ e_max, float* __restrict__ denom,
    float* __restrict__ agg, int n)
{
    __shared__ float Wl[D_IN * D_OUT];   // 16 KiB
    __shared__ float xdl[8][D_IN];       // 4 KiB
    __shared__ float vs[D_IN], vd[D_IN];

    int tid = threadIdx.x;
    for (int i = tid; i < D_IN * D_OUT; i += 256) Wl[i] = W_src[i];
    if (tid < D_IN) { vs[tid] = v_src[tid]; vd[tid] = v_dst[tid]; }
    __syncthreads();

    int loc  = tid >> 5;        // 0..7
    int lane = tid & 31;        // 0..31
    int node = blockIdx.x * 8 + loc;

    if (node < n) {
        const float4* xr = (const float4*)(x      + (size_t)node * D_IN);
        const float4* dr = (const float4*)(drop_u + (size_t)node * D_IN);
        float4 xv = xr[lane];
        float4 dv = dr[lane];
        float4 xd4;
        xd4.x = dv.x > DROP_P ? xv.x * KEEP_SCALE : 0.f;
        xd4.y = dv.y > DROP_P ? xv.y * KEEP_SCALE : 0.f;
        xd4.z = dv.z > DROP_P ? xv.z * KEEP_SCALE : 0.f;
        xd4.w = dv.w > DROP_P ? xv.w * KEEP_SCALE : 0.f;
        ((float4*)xdl[loc])[lane] = xd4;

        int kb = lane * 4;
        float ps = xd4.x * vs[kb] + xd4.y * vs[kb + 1] + xd4.z * vs[kb + 2] + xd4.w * vs[kb + 3];
        float pd = xd4.x * vd[kb] + xd4.y * vd[kb + 1] + xd4.z * vd[kb + 2] + xd4.w * vd[kb + 3];
        #pragma unroll
        for (int off = 16; off; off >>= 1) {
            ps += __shfl_xor(ps, off);
            pd += __shfl_xor(pd, off);
        }
        if (lane == 0) {
            a_src[node] = ps;
            a_dst[node] = pd;
            e_max[node] = -3.0e38f;
            denom[node] = 0.f;
        }
    }
    __syncthreads();

    if (node < n) {
        const float* xrow = xdl[loc];
        float acc = 0.f;
        #pragma unroll 8
        for (int k = 0; k < D_IN; ++k)
            acc += xrow[k] * Wl[k * D_OUT + lane];
        h_src[(size_t)node * D_OUT + lane] = acc;
        agg[(size_t)node * D_OUT + lane]   = 0.f;   // init aggregation buffer
    }
}

// KB: per-edge raw score + leaky relu; store score; atomic max into e_max[dst]
__global__ void k_edge_score(const int* __restrict__ ei, int E, int n,
                             const float* __restrict__ a_src, const float* __restrict__ a_dst,
                             float* __restrict__ score_out, float* __restrict__ e_max)
{
    int total = E + n;
    int i = blockIdx.x * blockDim.x + threadIdx.x;
    if (i >= total) return;
    int s, d;
    if (i < E) { s = ei[i]; d = ei[E + i]; }
    else       { s = d = i - E; }
    float e = a_src[s] + a_dst[d];
    e = e > 0.f ? e : NEG_SLOPE * e;
    score_out[i] = e;
    atomicMaxF(&e_max[d], e);
}

// KC: e_exp = exp(e - e_max[dst]); atomicAdd into denom[dst]
__global__ void k_edge_exp(const int* __restrict__ ei, int E, int n,
                           const float* __restrict__ e_max,
                           float* __restrict__ score_io, float* __restrict__ denom)
{
    int total = E + n;
    int i = blockIdx.x * blockDim.x + threadIdx.x;
    if (i >= total) return;
    int d = (i < E) ? ei[E + i] : (i - E);
    float ex = expf(score_io[i] - e_max[d]);
    score_io[i] = ex;
    atomicAdd(&denom[d], ex);
}

// KD: alpha = e_exp/denom[dst] (write final alpha); scatter-add h_src[src]*alpha
//     8 edges per 256-thread block, 32 lanes (one per channel) per edge.
__global__ __launch_bounds__(256) void k_edge_agg(
    const int* __restrict__ ei, int E, int n,
    const float* __restrict__ h_src, const float* __restrict__ denom,
    float* __restrict__ alpha_io, float* __restrict__ agg)
{
    int tid  = threadIdx.x;
    int loc  = tid >> 5;
    int lane = tid & 31;
    int i = blockIdx.x * 8 + loc;
    int total = E + n;
    if (i >= total) return;
    int s, d;
    if (i < E) { s = ei[i]; d = ei[E + i]; }
    else       { s = d = i - E; }
    float alpha = alpha_io[i] / denom[d];
    if (lane == 0) alpha_io[i] = alpha;
    float m = h_src[(size_t)s * D_OUT + lane] * alpha;
    atomicAdd(&agg[(size_t)d * D_OUT + lane], m);
}

// KE: out = agg + bias_gat; out += out@W_lin + b_lin; relu; log_softmax; overwrite
__global__ __launch_bounds__(256) void k_final(
    const float* __restrict__ bias_gat, const float* __restrict__ W_lin,
    const float* __restrict__ b_lin, float* __restrict__ io, int n)
{
    __shared__ float Wl[D_OUT * D_OUT];  // 4 KiB
    __shared__ float ul[8][D_OUT];

    int tid = threadIdx.x;
    for (int i = tid; i < D_OUT * D_OUT; i += 256) Wl[i] = W_lin[i];
    __syncthreads();

    int loc  = tid >> 5;
    int lane = tid & 31;
    int node = blockIdx.x * 8 + loc;

    float u = 0.f;
    if (node < n) u = io[(size_t)node * D_OUT + lane] + bias_gat[lane];
    ul[loc][lane] = u;
    __syncthreads();

    float r = u + b_lin[lane];
    #pragma unroll 8
    for (int k = 0; k < D_OUT; ++k)
        r += ul[loc][k] * Wl[k * D_OUT + lane];
    r = fmaxf(r, 0.f);

    // log_softmax across the 32 lanes of this node
    float m = r;
    #pragma unroll
    for (int off = 16; off; off >>= 1) m = fmaxf(m, __shfl_xor(m, off));
    float ex = expf(r - m);
    float ssum = ex;
    #pragma unroll
    for (int off = 16; off; off >>= 1) ssum += __shfl_xor(ssum, off);
    float logp = r - m - logf(ssum);

    if (node < n) io[(size_t)node * D_OUT + lane] = logp;
}

extern "C" void kernel_launch(void* const* d_in, const int* in_sizes, int n_in,
                              void* d_out, int out_size, void* d_ws, size_t ws_size,
                              hipStream_t stream)
{
    const float* x        = (const float*)d_in[0];
    const int*   ei       = (const int*)  d_in[1];
    const float* drop_u   = (const float*)d_in[2];
    const float* W_src    = (const float*)d_in[3];
    const float* W_dst    = (const float*)d_in[4];
    const float* att_src  = (const float*)d_in[5];
    const float* att_dst  = (const float*)d_in[6];
    const float* bias_gat = (const float*)d_in[7];
    const float* W_lin    = (const float*)d_in[8];
    const float* b_lin    = (const float*)d_in[9];

    const int N = in_sizes[0] / D_IN;      // 100000
    const int E = in_sizes[1] / 2;         // 1600000
    const int total = E + N;               // 1700000

    // workspace layout (floats)
    float* ws     = (float*)d_ws;
    float* v_src  = ws;                    // 128
    float* v_dst  = ws + 128;              // 128
    float* h_src  = ws + 256;              // N*32
    float* a_src  = h_src + (size_t)N * D_OUT;  // N
    float* a_dst  = a_src + N;             // N
    float* e_max  = a_dst + N;             // N
    float* denom  = e_max + N;             // N

    // output layout: logp [N*32] then alpha [E+N]
    float* logp_out  = (float*)d_out;           // also used as agg accumulator
    float* alpha_out = (float*)d_out + (size_t)N * D_OUT;  // also used as score/e_exp scratch

    k_fold<<<1, 128, 0, stream>>>(W_src, W_dst, att_src, att_dst, v_src, v_dst);

    int nodeBlocks = (N + 7) / 8;
    k_nodes<<<nodeBlocks, 256, 0, stream>>>(x, drop_u, W_src, v_src, v_dst,
                                            h_src, a_src, a_dst, e_max, denom,
                                            logp_out, N);

    int eb = (total + 255) / 256;
    k_edge_score<<<eb, 256, 0, stream>>>(ei, E, N, a_src, a_dst, alpha_out, e_max);
    k_edge_exp<<<eb, 256, 0, stream>>>(ei, E, N, e_max, alpha_out, denom);

    int aggBlocks = (total + 7) / 8;
    k_edge_agg<<<aggBlocks, 256, 0, stream>>>(ei, E, N, h_src, denom, alpha_out, logp_out);

    k_final<<<nodeBlocks, 256, 0, stream>>>(bias_gat, W_lin, b_lin, logp_out, N);
}

// Round 2
// 347.855 us; speedup vs baseline: 1.2481x; 1.2481x over previous
//
#include <hip/hip_runtime.h>
#include <math.h>

#define D_IN   128
#define D_OUT  32
#define NEG_SLOPE 0.2f
#define DROP_P 0.6f
#define KEEP_SCALE 2.5f   // 1/(1-0.6)
#define CAP    128        // per-node LDS edge cache (max in-degree ~50 for Poisson(17))

__device__ __forceinline__ void atomicMaxF(float* addr, float v) {
    if (v >= 0.0f) atomicMax((int*)addr, __float_as_int(v));
    else           atomicMin((unsigned int*)addr, __float_as_uint(v));
}

// K0: fold attention vectors: v_src[k] = sum_c W_src[k,c]*att_src[c]; same for dst
__global__ void k_fold(const float* __restrict__ W_src, const float* __restrict__ W_dst,
                       const float* __restrict__ att_src, const float* __restrict__ att_dst,
                       float* __restrict__ v_src, float* __restrict__ v_dst) {
    int k = threadIdx.x;
    if (k >= D_IN) return;
    float s = 0.f, d = 0.f;
    #pragma unroll
    for (int c = 0; c < D_OUT; ++c) {
        s += W_src[k * D_OUT + c] * att_src[c];
        d += W_dst[k * D_OUT + c] * att_dst[c];
    }
    v_src[k] = s;
    v_dst[k] = d;
}

// KA: per-node dropout + h_src + a_src/a_dst. 8 nodes/block, 32 lanes/node.
__global__ __launch_bounds__(256) void k_nodes(
    const float* __restrict__ x, const float* __restrict__ drop_u,
    const float* __restrict__ W_src,
    const float* __restrict__ v_src, const float* __restrict__ v_dst,
    float* __restrict__ h_src, float* __restrict__ a_src, float* __restrict__ a_dst,
    float* __restrict__ e_max, float* __restrict__ denom,
    float* __restrict__ agg, int n, int init_aux)
{
    __shared__ float Wl[D_IN * D_OUT];
    __shared__ float xdl[8][D_IN];
    __shared__ float vs[D_IN], vd[D_IN];

    int tid = threadIdx.x;
    for (int i = tid; i < D_IN * D_OUT; i += 256) Wl[i] = W_src[i];
    if (tid < D_IN) { vs[tid] = v_src[tid]; vd[tid] = v_dst[tid]; }
    __syncthreads();

    int loc  = tid >> 5;
    int lane = tid & 31;
    int node = blockIdx.x * 8 + loc;

    if (node < n) {
        const float4* xr = (const float4*)(x      + (size_t)node * D_IN);
        const float4* dr = (const float4*)(drop_u + (size_t)node * D_IN);
        float4 xv = xr[lane];
        float4 dv = dr[lane];
        float4 xd4;
        xd4.x = dv.x > DROP_P ? xv.x * KEEP_SCALE : 0.f;
        xd4.y = dv.y > DROP_P ? xv.y * KEEP_SCALE : 0.f;
        xd4.z = dv.z > DROP_P ? xv.z * KEEP_SCALE : 0.f;
        xd4.w = dv.w > DROP_P ? xv.w * KEEP_SCALE : 0.f;
        ((float4*)xdl[loc])[lane] = xd4;

        int kb = lane * 4;
        float ps = xd4.x * vs[kb] + xd4.y * vs[kb + 1] + xd4.z * vs[kb + 2] + xd4.w * vs[kb + 3];
        float pd = xd4.x * vd[kb] + xd4.y * vd[kb + 1] + xd4.z * vd[kb + 2] + xd4.w * vd[kb + 3];
        #pragma unroll
        for (int off = 16; off; off >>= 1) {
            ps += __shfl_xor(ps, off);
            pd += __shfl_xor(pd, off);
        }
        if (lane == 0) {
            a_src[node] = ps;
            a_dst[node] = pd;
            if (init_aux) { e_max[node] = -3.0e38f; denom[node] = 0.f; }
        }
    }
    __syncthreads();

    if (node < n) {
        const float* xrow = xdl[loc];
        float acc = 0.f;
        #pragma unroll 8
        for (int k = 0; k < D_IN; ++k)
            acc += xrow[k] * Wl[k * D_OUT + lane];
        h_src[(size_t)node * D_OUT + lane] = acc;
        if (init_aux) agg[(size_t)node * D_OUT + lane] = 0.f;
    }
}

// ---------------- CSR build ----------------
__global__ void k_zero(int* __restrict__ p, int n) {
    int i = blockIdx.x * blockDim.x + threadIdx.x;
    if (i < n) p[i] = 0;
}

__global__ void k_hist(const int* __restrict__ ei, int E, int n, int* __restrict__ cnt) {
    int i = blockIdx.x * blockDim.x + threadIdx.x;
    int total = E + n;
    if (i >= total) return;
    int d = (i < E) ? ei[E + i] : (i - E);
    atomicAdd(&cnt[d], 1);
}

// chunk-local exclusive scan; 256 threads x 4 elems = 1024/chunk; in-place safe
__global__ __launch_bounds__(256) void k_scan1(int* __restrict__ data, int n, int* __restrict__ part) {
    __shared__ int sums[256];
    int t = threadIdx.x;
    int base = blockIdx.x * 1024 + t * 4;
    int v0 = 0, v1 = 0, v2 = 0, v3 = 0;
    if (base + 0 < n) v0 = data[base + 0];
    if (base + 1 < n) v1 = data[base + 1];
    if (base + 2 < n) v2 = data[base + 2];
    if (base + 3 < n) v3 = data[base + 3];
    int s = v0 + v1 + v2 + v3;
    sums[t] = s;
    __syncthreads();
    for (int off = 1; off < 256; off <<= 1) {
        int v = (t >= off) ? sums[t - off] : 0;
        __syncthreads();
        sums[t] += v;
        __syncthreads();
    }
    int excl = sums[t] - s;
    if (t == 255) part[blockIdx.x] = sums[255];
    if (base + 0 < n) data[base + 0] = excl;
    if (base + 1 < n) data[base + 1] = excl + v0;
    if (base + 2 < n) data[base + 2] = excl + v0 + v1;
    if (base + 3 < n) data[base + 3] = excl + v0 + v1 + v2;
}

__global__ void k_scan2(int* __restrict__ part, int nb) {
    if (blockIdx.x == 0 && threadIdx.x == 0) {
        int acc = 0;
        for (int i = 0; i < nb; ++i) { int v = part[i]; part[i] = acc; acc += v; }
    }
}

__global__ void k_scan3(int* __restrict__ offs, const int* __restrict__ part,
                        int n, int total, int* __restrict__ cursor) {
    int i = blockIdx.x * blockDim.x + threadIdx.x;
    if (i < n) {
        int v = offs[i] + part[i >> 10];
        offs[i] = v;
        cursor[i] = v;
    }
    if (i == 0) offs[n] = total;
}

__global__ void k_scatter(const int* __restrict__ ei, int E, int n,
                          int* __restrict__ cursor, int2* __restrict__ sorted) {
    int i = blockIdx.x * blockDim.x + threadIdx.x;
    int total = E + n;
    if (i >= total) return;
    int s, d;
    if (i < E) { s = ei[i]; d = ei[E + i]; }
    else       { s = d = i - E; }
    int pos = atomicAdd(&cursor[d], 1);
    sorted[pos] = make_int2(s, i);
}

// Fused per-node softmax + aggregation. 8 nodes/block, 32 lanes/node, no atomics.
__global__ __launch_bounds__(256) void k_node_agg(
    const int2* __restrict__ sorted, const int* __restrict__ offs,
    const float* __restrict__ a_src, const float* __restrict__ a_dst,
    const float* __restrict__ h_src,
    float* __restrict__ alpha_out, float* __restrict__ out, int n)
{
    __shared__ float s_al[8][CAP];
    __shared__ int   s_src[8][CAP];
    __shared__ int   s_idx[8][CAP];

    int tid  = threadIdx.x;
    int loc  = tid >> 5;
    int lane = tid & 31;
    int nd   = blockIdx.x * 8 + loc;
    if (nd >= n) return;

    int off = offs[nd];
    int deg = offs[nd + 1] - off;
    float adst = a_dst[nd];

    // pass 1: max (edge-parallel), cache src/idx in LDS
    float m = -3.0e38f;
    for (int j = lane; j < deg; j += 32) {
        int2 p = sorted[off + j];
        float e = a_src[p.x] + adst;
        e = e > 0.f ? e : NEG_SLOPE * e;
        m = fmaxf(m, e);
        if (j < CAP) { s_src[loc][j] = p.x; s_idx[loc][j] = p.y; }
    }
    #pragma unroll
    for (int o = 16; o; o >>= 1) m = fmaxf(m, __shfl_xor(m, o));

    // pass 2: exp + sum
    float ssum = 0.f;
    for (int j = lane; j < deg; j += 32) {
        int sidx = (j < CAP) ? s_src[loc][j] : sorted[off + j].x;
        float e = a_src[sidx] + adst;
        e = e > 0.f ? e : NEG_SLOPE * e;
        float ex = expf(e - m);
        ssum += ex;
        if (j < CAP) s_al[loc][j] = ex;
    }
    #pragma unroll
    for (int o = 16; o; o >>= 1) ssum += __shfl_xor(ssum, o);
    float inv = 1.0f / ssum;

    // pass 3: write alpha (edge-parallel), normalize LDS copy
    for (int j = lane; j < deg; j += 32) {
        if (j < CAP) {
            float al = s_al[loc][j] * inv;
            s_al[loc][j] = al;
            alpha_out[s_idx[loc][j]] = al;
        } else {
            int2 p = sorted[off + j];
            float e = a_src[p.x] + adst;
            e = e > 0.f ? e : NEG_SLOPE * e;
            alpha_out[p.y] = expf(e - m) * inv;
        }
    }
    // 32-lane groups are halves of one wave: LDS write->read is lockstep-safe.

    // phase B: channel-parallel aggregation, serial over edges
    float acc = 0.f;
    for (int j = 0; j < deg; ++j) {
        int sidx; float al;
        if (j < CAP) { sidx = s_src[loc][j]; al = s_al[loc][j]; }
        else {
            int2 p = sorted[off + j];
            sidx = p.x;
            float e = a_src[p.x] + adst;
            e = e > 0.f ? e : NEG_SLOPE * e;
            al = expf(e - m) * inv;
        }
        acc += h_src[(size_t)sidx * D_OUT + lane] * al;
    }
    out[(size_t)nd * D_OUT + lane] = acc;
}

// ---------------- fallback (round-1) edge kernels ----------------
__global__ void k_edge_score(const int* __restrict__ ei, int E, int n,
                             const float* __restrict__ a_src, const float* __restrict__ a_dst,
                             float* __restrict__ score_out, float* __restrict__ e_max)
{
    int total = E + n;
    int i = blockIdx.x * blockDim.x + threadIdx.x;
    if (i >= total) return;
    int s, d;
    if (i < E) { s = ei[i]; d = ei[E + i]; }
    else       { s = d = i - E; }
    float e = a_src[s] + a_dst[d];
    e = e > 0.f ? e : NEG_SLOPE * e;
    score_out[i] = e;
    atomicMaxF(&e_max[d], e);
}

__global__ void k_edge_exp(const int* __restrict__ ei, int E, int n,
                           const float* __restrict__ e_max,
                           float* __restrict__ score_io, float* __restrict__ denom)
{
    int total = E + n;
    int i = blockIdx.x * blockDim.x + threadIdx.x;
    if (i >= total) return;
    int d = (i < E) ? ei[E + i] : (i - E);
    float ex = expf(score_io[i] - e_max[d]);
    score_io[i] = ex;
    atomicAdd(&denom[d], ex);
}

__global__ __launch_bounds__(256) void k_edge_agg(
    const int* __restrict__ ei, int E, int n,
    const float* __restrict__ h_src, const float* __restrict__ denom,
    float* __restrict__ alpha_io, float* __restrict__ agg)
{
    int tid  = threadIdx.x;
    int loc  = tid >> 5;
    int lane = tid & 31;
    int i = blockIdx.x * 8 + loc;
    int total = E + n;
    if (i >= total) return;
    int s, d;
    if (i < E) { s = ei[i]; d = ei[E + i]; }
    else       { s = d = i - E; }
    float alpha = alpha_io[i] / denom[d];
    if (lane == 0) alpha_io[i] = alpha;
    float m = h_src[(size_t)s * D_OUT + lane] * alpha;
    atomicAdd(&agg[(size_t)d * D_OUT + lane], m);
}

// KE: out = agg + bias_gat; out += out@W_lin + b_lin; relu; log_softmax
__global__ __launch_bounds__(256) void k_final(
    const float* __restrict__ bias_gat, const float* __restrict__ W_lin,
    const float* __restrict__ b_lin, float* __restrict__ io, int n)
{
    __shared__ float Wl[D_OUT * D_OUT];
    __shared__ float ul[8][D_OUT];

    int tid = threadIdx.x;
    for (int i = tid; i < D_OUT * D_OUT; i += 256) Wl[i] = W_lin[i];
    __syncthreads();

    int loc  = tid >> 5;
    int lane = tid & 31;
    int node = blockIdx.x * 8 + loc;

    float u = 0.f;
    if (node < n) u = io[(size_t)node * D_OUT + lane] + bias_gat[lane];
    ul[loc][lane] = u;
    __syncthreads();

    float r = u + b_lin[lane];
    #pragma unroll 8
    for (int k = 0; k < D_OUT; ++k)
        r += ul[loc][k] * Wl[k * D_OUT + lane];
    r = fmaxf(r, 0.f);

    float m = r;
    #pragma unroll
    for (int off = 16; off; off >>= 1) m = fmaxf(m, __shfl_xor(m, off));
    float ex = expf(r - m);
    float ssum = ex;
    #pragma unroll
    for (int off = 16; off; off >>= 1) ssum += __shfl_xor(ssum, off);
    float logp = r - m - logf(ssum);

    if (node < n) io[(size_t)node * D_OUT + lane] = logp;
}

extern "C" void kernel_launch(void* const* d_in, const int* in_sizes, int n_in,
                              void* d_out, int out_size, void* d_ws, size_t ws_size,
                              hipStream_t stream)
{
    const float* x        = (const float*)d_in[0];
    const int*   ei       = (const int*)  d_in[1];
    const float* drop_u   = (const float*)d_in[2];
    const float* W_src    = (const float*)d_in[3];
    const float* W_dst    = (const float*)d_in[4];
    const float* att_src  = (const float*)d_in[5];
    const float* att_dst  = (const float*)d_in[6];
    const float* bias_gat = (const float*)d_in[7];
    const float* W_lin    = (const float*)d_in[8];
    const float* b_lin    = (const float*)d_in[9];

    const int N = in_sizes[0] / D_IN;      // 100000
    const int E = in_sizes[1] / 2;         // 1600000
    const int total = E + N;

    float* ws = (float*)d_ws;

    // common layout
    float* v_src = ws;                 // 128
    float* v_dst = ws + 128;           // 128
    float* h_src = ws + 256;           // 32N
    float* a_src = h_src + (size_t)N * D_OUT;
    float* a_dst = a_src + N;

    float* logp_out  = (float*)d_out;
    float* alpha_out = (float*)d_out + (size_t)N * D_OUT;

    // CSR layout after a_dst
    size_t idx = 256 + (size_t)N * D_OUT + 2 * (size_t)N;
    int* offs   = (int*)(ws + idx);   idx += (size_t)N + 2;   // N+1 (+1 pad)
    int* cursor = (int*)(ws + idx);   idx += (size_t)N;
    int* part   = (int*)(ws + idx);   idx += 256;
    idx = (idx + 1) & ~(size_t)1;                              // 8B-align
    int2* sorted = (int2*)(ws + idx); idx += 2 * (size_t)total;
    size_t need_bytes = idx * sizeof(float);

    int nodeBlocks = (N + 7) / 8;
    int eb = (total + 255) / 256;

    k_fold<<<1, 128, 0, stream>>>(W_src, W_dst, att_src, att_dst, v_src, v_dst);

    if (ws_size >= need_bytes) {
        // CSR path: no float atomics anywhere
        k_nodes<<<nodeBlocks, 256, 0, stream>>>(x, drop_u, W_src, v_src, v_dst,
                                                h_src, a_src, a_dst,
                                                nullptr, nullptr, nullptr, N, 0);
        k_zero<<<(N + 255) / 256, 256, 0, stream>>>(offs, N);
        k_hist<<<eb, 256, 0, stream>>>(ei, E, N, offs);
        int nb = (N + 1023) / 1024;
        k_scan1<<<nb, 256, 0, stream>>>(offs, N, part);
        k_scan2<<<1, 64, 0, stream>>>(part, nb);
        k_scan3<<<(N + 255) / 256, 256, 0, stream>>>(offs, part, N, total, cursor);
        k_scatter<<<eb, 256, 0, stream>>>(ei, E, N, cursor, sorted);
        k_node_agg<<<nodeBlocks, 256, 0, stream>>>(sorted, offs, a_src, a_dst,
                                                   h_src, alpha_out, logp_out, N);
    } else {
        // fallback: round-1 atomic path
        float* e_max = a_dst + N;
        float* denom = e_max + N;
        k_nodes<<<nodeBlocks, 256, 0, stream>>>(x, drop_u, W_src, v_src, v_dst,
                                                h_src, a_src, a_dst,
                                                e_max, denom, logp_out, N, 1);
        k_edge_score<<<eb, 256, 0, stream>>>(ei, E, N, a_src, a_dst, alpha_out, e_max);
        k_edge_exp<<<eb, 256, 0, stream>>>(ei, E, N, e_max, alpha_out, denom);
        int aggBlocks = (total + 7) / 8;
        k_edge_agg<<<aggBlocks, 256, 0, stream>>>(ei, E, N, h_src, denom, alpha_out, logp_out);
    }

    k_final<<<nodeBlocks, 256, 0, stream>>>(bias_gat, W_lin, b_lin, logp_out, N);
}